// Round 8
// baseline (208.935 us; speedup 1.0000x reference)
//
#include <hip/hip_runtime.h>

#define BOUND 1e-6f
#define HALF_PI 1.57079632679489662f
#define LOG2E 1.44269504088896341f

// DPP helper: masked/out-of-range lanes receive `oldv` (1.0 = mult identity).
#define UPD_DPP(oldv, srcv, ctrl, rmask)                                        \
  __int_as_float(__builtin_amdgcn_update_dpp(                                   \
      __float_as_int(oldv), __float_as_int(srcv), (ctrl), (rmask), 0xF, false))

// Inclusive multiplicative scan across 64 lanes, pure VALU (validated R2-R7).
__device__ __forceinline__ float wave_incl_prod(float x) {
    x *= UPD_DPP(1.0f, x, 0x111, 0xF);  // row_shr:1
    x *= UPD_DPP(1.0f, x, 0x112, 0xF);  // row_shr:2
    x *= UPD_DPP(1.0f, x, 0x114, 0xF);  // row_shr:4
    x *= UPD_DPP(1.0f, x, 0x118, 0xF);  // row_shr:8
    x *= UPD_DPP(1.0f, x, 0x142, 0xA);  // row_bcast:15 -> rows 1,3
    x *= UPD_DPP(1.0f, x, 0x143, 0xC);  // row_bcast:31 -> rows 2,3
    return x;
}

// Issue-cycle-minimized variant (kernel is SIMD-issue-bound at ~272 cyc/row;
// this restructure gets ~178): R5 row-ownership (lane owns cols 4l..4l+3,
// float4 loads, intra-lane prefix products => per-element exclusive prefix is
// FREE -- no rcp/mul epilogue; ONE wave scan, not four) + LDS-staged
// full-line stores (R5, -15%) + poly sin/cos in u = pi/2 - a (R7) +
// sigmoid as u = amp*rcp(1+exp2(c*x)), c = scaling*log2(e) + BOUND folded
// into poly constants + exclusive shift via DPP wave_shr:1 (0x138, old=1.0).
// out[j]   = radius * prod_{i<j}(sin(a_i)+B) * (cos(a_j)+B),  j < 256
// out[256] = radius * prod_{i<256}(sin(a_i)+B)
__global__ __launch_bounds__(512) void spherize_kernel(
    const float* __restrict__ x,
    const float* __restrict__ p_phiL,
    const float* __restrict__ p_radius,
    const float* __restrict__ p_scaling,
    float* __restrict__ out,
    int n_rows)
{
    __shared__ float lds[32 * 257];   // 32896 B (128B-multiple => full lines)

    const float phi_L   = p_phiL[0];
    const float radius  = p_radius[0];
    const float cexp    = p_scaling[0] * LOG2E;  // exp(s*x) = exp2(cexp*x)
    const float amp     = HALF_PI - phi_L;

    const int tid  = threadIdx.x;
    const int lane = tid & 63;
    const int wave = tid >> 6;              // 0..7
    const int row0 = blockIdx.x * 32;       // block's first row
    const int wrow = row0 + wave * 4;       // this wave's first row

    const int nr_blk = min(32, n_rows - row0);        // rows in this block
    const int nr_w   = min(4, max(0, n_rows - wrow)); // rows for this wave

    // ---- load this wave's 4 rows up front (float4, 1KB/instr coalesced) ----
    float4 xv[4];
    const float* xb = x + (size_t)wrow * 256 + lane * 4;
    #pragma unroll
    for (int i = 0; i < 4; ++i)
        if (i < nr_w) xv[i] = *reinterpret_cast<const float4*>(xb + i * 256);

    // ---- compute rows into LDS ----
    #pragma unroll
    for (int i = 0; i < 4; ++i) {
        if (i >= nr_w) break;
        const float* xp = &xv[i].x;
        float s[4], c[4];
        #pragma unroll
        for (int k = 0; k < 4; ++k) {
            // u = pi/2 - a = amp*(1 - sigmoid(s*x)) = amp / (1 + exp(s*x))
            float e  = __builtin_amdgcn_exp2f(cexp * xp[k]);
            float u  = amp * __builtin_amdgcn_rcpf(1.0f + e);
            float u2 = u * u;
            // sin(a)=cos(u), cos(a)=sin(u); BOUND folded into constants
            s[k] = fmaf(u2, fmaf(u2, 4.16666667e-2f, -0.5f), 1.0f + BOUND);
            float p = fmaf(u2, fmaf(u2, 8.33333333e-3f, -1.66666667e-1f), 1.0f);
            c[k] = fmaf(u, p, BOUND);
        }

        // intra-lane prefix products (exclusive prefixes q* come free)
        float q1 = s[0];
        float q2 = q1 * s[1];
        float q3 = q2 * s[2];
        float t  = q3 * s[3];
        float scan = wave_incl_prod(t);               // inclusive over lanes
        float excl = UPD_DPP(1.0f, scan, 0x138, 0xF); // wave_shr:1, lane0=1.0
        float base = radius * excl;

        float* lrow = lds + (wave * 4 + i) * 257 + lane * 4;
        lrow[0] = base * c[0];
        lrow[1] = base * q1 * c[1];
        lrow[2] = base * q2 * c[2];
        lrow[3] = base * q3 * c[3];
        if (lane == 63)
            lrow[4] = radius * scan;                  // col 256: full product
    }
    __syncthreads();

    // ---- cooperative aligned full-line store of the block's region ----
    float* obase = out + (size_t)row0 * 257;
    if (nr_blk == 32) {
        // 32*257 = 8224 dwords = 2056 float4s, region 128B-aligned
        const float4* l4 = reinterpret_cast<const float4*>(lds);
        float4*       o4 = reinterpret_cast<float4*>(obase);
        o4[tid]        = l4[tid];
        o4[tid + 512]  = l4[tid + 512];
        o4[tid + 1024] = l4[tid + 1024];
        o4[tid + 1536] = l4[tid + 1536];
        if (tid < 8) o4[tid + 2048] = l4[tid + 2048];
    } else {
        // tail block (not hit for N=524288): safe dword cooperative store
        const int nd = nr_blk * 257;
        for (int i = tid; i < nd; i += 512) obase[i] = lds[i];
    }
}

extern "C" void kernel_launch(void* const* d_in, const int* in_sizes, int n_in,
                              void* d_out, int out_size, void* d_ws, size_t ws_size,
                              hipStream_t stream) {
    // inputs: 0=x [N,256], 1=W_theta, 2=W_phi, 3=b_phi, 4=phi_L, 5=radius, 6=scaling
    const float* x         = (const float*)d_in[0];
    const float* p_phiL    = (const float*)d_in[4];
    const float* p_radius  = (const float*)d_in[5];
    const float* p_scaling = (const float*)d_in[6];
    float* out = (float*)d_out;

    const int n_rows = in_sizes[0] / 256;
    const int blocks = (n_rows + 31) / 32;   // 16384 for N=524288

    spherize_kernel<<<blocks, 512, 0, stream>>>(x, p_phiL, p_radius, p_scaling,
                                                out, n_rows);
}

// Round 9
// 204.057 us; speedup vs baseline: 1.0239x; 1.0239x over previous
//
#include <hip/hip_runtime.h>

#define BOUND 1e-6f
#define HALF_PI 1.57079632679489662f
#define LOG2E 1.44269504088896341f

// DPP helper: masked/out-of-range lanes receive `oldv` (1.0 = mult identity).
#define UPD_DPP(oldv, srcv, ctrl, rmask)                                        \
  __int_as_float(__builtin_amdgcn_update_dpp(                                   \
      __float_as_int(oldv), __float_as_int(srcv), (ctrl), (rmask), 0xF, false))

// Inclusive multiplicative scan across 64 lanes, pure VALU (validated R2-R8).
__device__ __forceinline__ float wave_incl_prod(float x) {
    x *= UPD_DPP(1.0f, x, 0x111, 0xF);  // row_shr:1
    x *= UPD_DPP(1.0f, x, 0x112, 0xF);  // row_shr:2
    x *= UPD_DPP(1.0f, x, 0x114, 0xF);  // row_shr:4
    x *= UPD_DPP(1.0f, x, 0x118, 0xF);  // row_shr:8
    x *= UPD_DPP(1.0f, x, 0x142, 0xA);  // row_bcast:15 -> rows 1,3
    x *= UPD_DPP(1.0f, x, 0x143, 0xC);  // row_bcast:31 -> rows 2,3
    return x;
}

// R8 per-wave math, HALF-GRAIN blocks: 256 threads (4 waves) x 16 rows,
// LDS 16448 B -> 8 blocks/CU resident (vs 4) = 8 independent
// load->compute->store lifecycles per CU, 2x block-retirement rate, half-size
// barrier groups. Theory: block-grain burstiness (reads only injected on
// block turnover) was the post-R5 limiter; finer grain smooths the memory
// pipeline. Per-wave structure identical to R8 (4 rows, float4 loads,
// intra-lane prefix + one DPP scan, poly sin/cos, LDS-staged stores).
// out[j]   = radius * prod_{i<j}(sin(a_i)+B) * (cos(a_j)+B),  j < 256
// out[256] = radius * prod_{i<256}(sin(a_i)+B)
__global__ __launch_bounds__(256) void spherize_kernel(
    const float* __restrict__ x,
    const float* __restrict__ p_phiL,
    const float* __restrict__ p_radius,
    const float* __restrict__ p_scaling,
    float* __restrict__ out,
    int n_rows)
{
    __shared__ float lds[16 * 257];   // 16448 B

    const float phi_L   = p_phiL[0];
    const float radius  = p_radius[0];
    const float cexp    = p_scaling[0] * LOG2E;  // exp(s*x) = exp2(cexp*x)
    const float amp     = HALF_PI - phi_L;

    const int tid  = threadIdx.x;
    const int lane = tid & 63;
    const int wave = tid >> 6;              // 0..3
    const int row0 = blockIdx.x * 16;       // block's first row
    const int wrow = row0 + wave * 4;       // this wave's first row

    const int nr_blk = min(16, n_rows - row0);        // rows in this block
    const int nr_w   = min(4, max(0, n_rows - wrow)); // rows for this wave

    // ---- load this wave's 4 rows up front (float4, 1KB/instr coalesced) ----
    float4 xv[4];
    const float* xb = x + (size_t)wrow * 256 + lane * 4;
    #pragma unroll
    for (int i = 0; i < 4; ++i)
        if (i < nr_w) xv[i] = *reinterpret_cast<const float4*>(xb + i * 256);

    // ---- compute rows into LDS ----
    #pragma unroll
    for (int i = 0; i < 4; ++i) {
        if (i >= nr_w) break;
        const float* xp = &xv[i].x;
        float s[4], c[4];
        #pragma unroll
        for (int k = 0; k < 4; ++k) {
            // u = pi/2 - a = amp*(1 - sigmoid(s*x)) = amp / (1 + exp(s*x))
            float e  = __builtin_amdgcn_exp2f(cexp * xp[k]);
            float u  = amp * __builtin_amdgcn_rcpf(1.0f + e);
            float u2 = u * u;
            // sin(a)=cos(u), cos(a)=sin(u); BOUND folded into constants
            s[k] = fmaf(u2, fmaf(u2, 4.16666667e-2f, -0.5f), 1.0f + BOUND);
            float p = fmaf(u2, fmaf(u2, 8.33333333e-3f, -1.66666667e-1f), 1.0f);
            c[k] = fmaf(u, p, BOUND);
        }

        // intra-lane prefix products (exclusive prefixes q* come free)
        float q1 = s[0];
        float q2 = q1 * s[1];
        float q3 = q2 * s[2];
        float t  = q3 * s[3];
        float scan = wave_incl_prod(t);               // inclusive over lanes
        float excl = UPD_DPP(1.0f, scan, 0x138, 0xF); // wave_shr:1, lane0=1.0
        float base = radius * excl;

        float* lrow = lds + (wave * 4 + i) * 257 + lane * 4;
        lrow[0] = base * c[0];
        lrow[1] = base * q1 * c[1];
        lrow[2] = base * q2 * c[2];
        lrow[3] = base * q3 * c[3];
        if (lane == 63)
            lrow[4] = radius * scan;                  // col 256: full product
    }
    __syncthreads();

    // ---- cooperative aligned float4 store of the block's region ----
    // 16*257 = 4112 dwords = 1028 float4; region base 16B-aligned always.
    float* obase = out + (size_t)row0 * 257;
    if (nr_blk == 16) {
        const float4* l4 = reinterpret_cast<const float4*>(lds);
        float4*       o4 = reinterpret_cast<float4*>(obase);
        o4[tid]        = l4[tid];
        o4[tid + 256]  = l4[tid + 256];
        o4[tid + 512]  = l4[tid + 512];
        o4[tid + 768]  = l4[tid + 768];
        if (tid < 4) o4[tid + 1024] = l4[tid + 1024];
    } else {
        // tail block (not hit for N=524288): safe dword cooperative store
        const int nd = nr_blk * 257;
        for (int i = tid; i < nd; i += 256) obase[i] = lds[i];
    }
}

extern "C" void kernel_launch(void* const* d_in, const int* in_sizes, int n_in,
                              void* d_out, int out_size, void* d_ws, size_t ws_size,
                              hipStream_t stream) {
    // inputs: 0=x [N,256], 1=W_theta, 2=W_phi, 3=b_phi, 4=phi_L, 5=radius, 6=scaling
    const float* x         = (const float*)d_in[0];
    const float* p_phiL    = (const float*)d_in[4];
    const float* p_radius  = (const float*)d_in[5];
    const float* p_scaling = (const float*)d_in[6];
    float* out = (float*)d_out;

    const int n_rows = in_sizes[0] / 256;
    const int blocks = (n_rows + 15) / 16;   // 32768 for N=524288

    spherize_kernel<<<blocks, 256, 0, stream>>>(x, p_phiL, p_radius, p_scaling,
                                                out, n_rows);
}